// Round 2
// baseline (7503.660 us; speedup 1.0000x reference)
//
#include <hip/hip_runtime.h>

#define B 256
#define T 2048
#define HDIM 128

typedef _Float16 f16;
typedef _Float16 h2 __attribute__((ext_vector_type(2)));

__device__ __forceinline__ float dot2(h2 a, h2 b, float c) {
#if __has_builtin(__builtin_amdgcn_fdot2)
    return __builtin_amdgcn_fdot2(a, b, c, false);
#else
    return c + (float)a[0] * (float)b[0] + (float)a[1] * (float)b[1];
#endif
}

__device__ __forceinline__ float sigm(float x) { return 1.0f / (1.0f + __expf(-x)); }
__device__ __forceinline__ float tanh_(float x) {
    float e = __expf(-2.0f * fabsf(x));
    float t = (1.0f - e) / (1.0f + e);
    return copysignf(t, x);
}

__device__ __forceinline__ void bar() {
    // LDS-only barrier: order ds ops but do NOT drain vmcnt (keeps x-prefetch
    // loads and y-stores in flight across the barrier).
    asm volatile("s_waitcnt lgkmcnt(0)" ::: "memory");
    __builtin_amdgcn_s_barrier();
}

// ---------------- fc1: scent[B,T,3] -> x1[T,B,32] f16 (24 real + 8 zero pad) ---------
__global__ __launch_bounds__(256) void fc1_kernel(
    const float* __restrict__ scent,
    const float* __restrict__ W1, const float* __restrict__ b1,
    const float* __restrict__ W2, const float* __restrict__ b2,
    f16* __restrict__ x1) {
    int r = blockIdx.x * 256 + threadIdx.x;   // r = b*T + t
    int b = r >> 11, t = r & 2047;
    float s0 = scent[r * 3], s1 = scent[r * 3 + 1], s2 = scent[r * 3 + 2];
    float a[12];
#pragma unroll
    for (int i = 0; i < 12; i++) {
        float v = W1[i * 3] * s0 + W1[i * 3 + 1] * s1 + W1[i * 3 + 2] * s2 + b1[i];
        a[i] = fmaxf(v, 0.f);
    }
    union { f16 o[32]; uint4 u[4]; } U;
#pragma unroll
    for (int j = 0; j < 24; j++) {
        float v = b2[j];
#pragma unroll
        for (int i = 0; i < 12; i++) v = fmaf(W2[j * 12 + i], a[i], v);
        U.o[j] = (f16)fmaxf(v, 0.f);
    }
#pragma unroll
    for (int j = 24; j < 32; j++) U.o[j] = (f16)0.f;
    uint4* d4 = (uint4*)(x1 + ((size_t)t * B + b) * 32);
#pragma unroll
    for (int i = 0; i < 4; i++) d4[i] = U.u[i];
}

// ---------------- pack Wf1 f32 -> half2 ----------------
__global__ __launch_bounds__(256) void pack_kernel(const float* __restrict__ w,
                                                   unsigned int* __restrict__ o) {
    int i = blockIdx.x * 256 + threadIdx.x;
    if (i < 4096) {
        union { h2 h; unsigned int u; } U;
        U.h[0] = (f16)w[2 * i];
        U.h[1] = (f16)w[2 * i + 1];
        o[i] = U.u;
    }
}

// ---------------- fused LSTM layer: one block (1024 thr) per batch row ----------------
// thread tid: gate g = tid>>1 (512 gates), k-half s = tid&1.
// Per thread: K2 = (KIN+128)/2 f16 weights in VGPRs (f16-packed), one dot2 chain,
// one DPP shfl_xor(1) to complete the gate sum. No multi-level reduce, no AGPR pressure.
template <int KIN, int KREAL>
__global__ __launch_bounds__(1024, 4) void lstm_kernel(
    const f16* __restrict__ x,       // [T,B,KIN] f16
    const float* __restrict__ Wih,   // [512,KREAL]
    const float* __restrict__ Whh,   // [512,128]
    const float* __restrict__ bih, const float* __restrict__ bhh,
    f16* __restrict__ y,             // [T,B,128] f16 (may alias x: in-place)
    float* __restrict__ hT, float* __restrict__ cT) {  // [B,128] each
    constexpr int KTOT = KIN + HDIM;
    constexpr int K2 = KTOT / 2;
    constexpr int NCH = K2 / 8;          // uint4 chunks per thread
    __shared__ __align__(16) f16 kvec[KTOT];   // [x_t | h_{t-1}]
    __shared__ float gbuf[512];

    const int tid = threadIdx.x;
    const int bb = blockIdx.x;
    const int s = tid & 1;
    const int g = tid >> 1;

    // ---- per-thread weights: k in [s*K2, s*K2+K2), f16-packed, 4*NCH h2 = 2*NCH VGPR pairs
    union { uint4 u4[NCH]; h2 h[NCH * 4]; } W;
    if (KIN == KREAL) {
        // L2/L3: s==0 -> full Wih row, s==1 -> full Whh row (both 128 wide)
        const float4* src = (const float4*)((s == 0 ? Wih : Whh) + g * HDIM);
#pragma unroll
        for (int i = 0; i < NCH; i++) {
            float4 a = src[2 * i], bq = src[2 * i + 1];
            h2 p0, p1, p2, p3;
            p0[0] = (f16)a.x;  p0[1] = (f16)a.y;
            p1[0] = (f16)a.z;  p1[1] = (f16)a.w;
            p2[0] = (f16)bq.x; p2[1] = (f16)bq.y;
            p3[0] = (f16)bq.z; p3[1] = (f16)bq.w;
            W.h[4 * i + 0] = p0; W.h[4 * i + 1] = p1;
            W.h[4 * i + 2] = p2; W.h[4 * i + 3] = p3;
        }
    } else {
        // L1: generic predicated gather (one-time)
#pragma unroll
        for (int i = 0; i < NCH * 4; i++) {
            int k0 = s * K2 + 2 * i, k1 = k0 + 1;
            float w0, w1;
            if (k0 < KIN) w0 = (k0 < KREAL) ? Wih[g * KREAL + k0] : 0.f;
            else          w0 = Whh[g * HDIM + (k0 - KIN)];
            if (k1 < KIN) w1 = (k1 < KREAL) ? Wih[g * KREAL + k1] : 0.f;
            else          w1 = Whh[g * HDIM + (k1 - KIN)];
            h2 p; p[0] = (f16)w0; p[1] = (f16)w1;
            W.h[i] = p;
        }
    }
    const float bsum = bih[g] + bhh[g];
    float c = 0.f;

    // ---- x stagers: dedicated lanes in wave 8 (tid 512..512+KIN/2), one dword each ----
    constexpr int KIN2 = KIN / 2;
    const bool stager = (tid >= 512) && (tid < 512 + KIN2);
    const int sid = tid - 512;
    const unsigned int* xg = (const unsigned int*)x;

    if (tid < HDIM) kvec[KIN + tid] = (f16)0.f;   // h0 = 0
    if (stager) {
        unsigned int x0 = xg[(size_t)(0 * B + bb) * KIN2 + sid];
        ((unsigned int*)kvec)[sid] = x0;
    }
    unsigned int xr1 = 0, xr2 = 0;                // prefetch rows t+1, t+2
    if (stager) {
        xr1 = xg[(size_t)(1 * B + bb) * KIN2 + sid];
        int t2 = (2 < T) ? 2 : T - 1;
        xr2 = xg[(size_t)t2 * B * KIN2 + (size_t)bb * KIN2 + sid];
    }
    __syncthreads();

    for (int t = 0; t < T; t++) {
        // issue prefetch for row t+3 early (hides under dot compute)
        unsigned int xr3 = 0;
        if (stager) {
            int tn = (t + 3 < T) ? t + 3 : T - 1;
            xr3 = xg[(size_t)tn * B * KIN2 + (size_t)bb * KIN2 + sid];
        }

        // ---- dot: K2 f16, read kvec slice as b128 (2 distinct addrs/instr -> free) ----
        float acc = 0.f;
        const uint4* kp = (const uint4*)(kvec + s * K2);
#pragma unroll
        for (int i = 0; i < NCH; i++) {
            union { uint4 u; h2 h[4]; } S;
            S.u = kp[i];
            acc = dot2(W.h[4 * i + 0], S.h[0], acc);
            acc = dot2(W.h[4 * i + 1], S.h[1], acc);
            acc = dot2(W.h[4 * i + 2], S.h[2], acc);
            acc = dot2(W.h[4 * i + 3], S.h[3], acc);
        }
        // ---- complete gate sum: one DPP xor-1 exchange ----
        float v = acc + __shfl_xor(acc, 1) + bsum;

        // ---- activation (wave-uniform gate type: tid>>8; 2=g -> tanh) ----
        const int gt = tid >> 8;
        float act = (gt == 2) ? tanh_(v) : sigm(v);
        if (s == 0) gbuf[g] = act;     // 32 lanes/wave, distinct banks
        bar();

        // ---- c/h update (threads 0..127) ----
        if (tid < HDIM) {
            float gi = gbuf[tid], gf = gbuf[128 + tid], gg = gbuf[256 + tid], go = gbuf[384 + tid];
            c = gf * c + gi * gg;
            float hh = go * tanh_(c);
            kvec[KIN + tid] = (f16)hh;
            y[((size_t)t * B + bb) * HDIM + tid] = (f16)hh;
            if (t == T - 1) { hT[bb * HDIM + tid] = hh; cT[bb * HDIM + tid] = c; }
        }
        if (stager) {
            ((unsigned int*)kvec)[sid] = xr1;   // x_{t+1}
        }
        xr1 = xr2; xr2 = xr3;
        bar();
    }
}

// ---------------- fc2: y[T,B,128] f16 -> out[B,T,32] f32 ----------------
__global__ __launch_bounds__(256) void fc2_kernel(
    const f16* __restrict__ yin,
    const unsigned int* __restrict__ w1,  // [64][64] half2-packed Wf1
    const float* __restrict__ bf1,
    const float* __restrict__ Wf2,        // [32][64] f32
    const float* __restrict__ bf2,
    float* __restrict__ out) {
    int r = blockIdx.x * 256 + threadIdx.x;   // r = t*B + b
    union { uint4 u4[16]; h2 h[64]; } Y;
    {
        const uint4* yr4 = (const uint4*)(yin + (size_t)r * 128);
#pragma unroll
        for (int i = 0; i < 16; i++) Y.u4[i] = yr4[i];
    }
    float acc2[32];
#pragma unroll
    for (int i = 0; i < 32; i++) acc2[i] = 0.f;

    for (int cO = 0; cO < 64; cO++) {   // rolled: z1[cO] consumed immediately
        float a0 = bf1[cO], a1 = 0.f, a2 = 0.f, a3 = 0.f;
#pragma unroll
        for (int kk = 0; kk < 64; kk += 4) {
            union { unsigned int u; h2 h; } W0, W1x, W2x, W3;
            W0.u = w1[cO * 64 + kk];      a0 = dot2(W0.h,  Y.h[kk],     a0);
            W1x.u = w1[cO * 64 + kk + 1]; a1 = dot2(W1x.h, Y.h[kk + 1], a1);
            W2x.u = w1[cO * 64 + kk + 2]; a2 = dot2(W2x.h, Y.h[kk + 2], a2);
            W3.u = w1[cO * 64 + kk + 3];  a3 = dot2(W3.h,  Y.h[kk + 3], a3);
        }
        float a = fmaxf((a0 + a1) + (a2 + a3), 0.f);
#pragma unroll
        for (int c2 = 0; c2 < 32; c2++) acc2[c2] = fmaf(a, Wf2[c2 * 64 + cO], acc2[c2]);
    }
    float* orow = out + ((size_t)(r & 255) * T + (r >> 8)) * 32;
#pragma unroll
    for (int c2 = 0; c2 < 32; c2++) orow[c2] = fmaxf(acc2[c2] + bf2[c2], 0.f);
}

// ---------------- launch ----------------
extern "C" void kernel_launch(void* const* d_in, const int* in_sizes, int n_in,
                              void* d_out, int out_size, void* d_ws, size_t ws_size,
                              hipStream_t stream) {
    const float* scent = (const float*)d_in[0];
    const float* W1 = (const float*)d_in[1];
    const float* b1 = (const float*)d_in[2];
    const float* W2 = (const float*)d_in[3];
    const float* b2 = (const float*)d_in[4];
    const float* Wih[3] = {(const float*)d_in[5], (const float*)d_in[9], (const float*)d_in[13]};
    const float* Whh[3] = {(const float*)d_in[6], (const float*)d_in[10], (const float*)d_in[14]};
    const float* bihp[3] = {(const float*)d_in[7], (const float*)d_in[11], (const float*)d_in[15]};
    const float* bhhp[3] = {(const float*)d_in[8], (const float*)d_in[12], (const float*)d_in[16]};
    const float* Wf1 = (const float*)d_in[17];
    const float* bf1 = (const float*)d_in[18];
    const float* Wf2 = (const float*)d_in[19];
    const float* bf2 = (const float*)d_in[20];

    const size_t o_x1 = 0;
    const size_t o_y  = 33554432;               // T*B*32*2
    const size_t o_w1 = o_y + 134217728;        // T*B*128*2
    const size_t need = o_w1 + 16384;
    if (ws_size < need) return;

    char* ws = (char*)d_ws;
    f16* x1 = (f16*)(ws + o_x1);                // [T,B,32]
    f16* yb = (f16*)(ws + o_y);                 // [T,B,128], reused in-place per layer
    unsigned int* w1p = (unsigned int*)(ws + o_w1);

    float* out = (float*)d_out;
    float* hO = out + (size_t)B * T * 32;
    float* cO = hO + 3 * B * HDIM;

    pack_kernel<<<16, 256, 0, stream>>>(Wf1, w1p);
    fc1_kernel<<<(B * T) / 256, 256, 0, stream>>>(scent, W1, b1, W2, b2, x1);
    lstm_kernel<32, 24><<<B, 1024, 0, stream>>>(x1, Wih[0], Whh[0], bihp[0], bhhp[0],
                                                yb, hO, cO);
    lstm_kernel<128, 128><<<B, 1024, 0, stream>>>(yb, Wih[1], Whh[1], bihp[1], bhhp[1],
                                                  yb, hO + B * HDIM, cO + B * HDIM);
    lstm_kernel<128, 128><<<B, 1024, 0, stream>>>(yb, Wih[2], Whh[2], bihp[2], bhhp[2],
                                                  yb, hO + 2 * B * HDIM, cO + 2 * B * HDIM);
    fc2_kernel<<<(B * T) / 256, 256, 0, stream>>>(yb, w1p, bf1, Wf2, bf2, out);
}

// Round 3
// 6100.558 us; speedup vs baseline: 1.2300x; 1.2300x over previous
//
#include <hip/hip_runtime.h>

#define B 256
#define T 2048
#define HDIM 128

typedef _Float16 f16;
typedef _Float16 h2 __attribute__((ext_vector_type(2)));

__device__ __forceinline__ float dot2(h2 a, h2 b, float c) {
#if __has_builtin(__builtin_amdgcn_fdot2)
    return __builtin_amdgcn_fdot2(a, b, c, false);
#else
    return c + (float)a[0] * (float)b[0] + (float)a[1] * (float)b[1];
#endif
}

__device__ __forceinline__ float sigm(float x) { return 1.0f / (1.0f + __expf(-x)); }
__device__ __forceinline__ float tanh_(float x) {
    float e = __expf(-2.0f * fabsf(x));
    float t = (1.0f - e) / (1.0f + e);
    return copysignf(t, x);
}

__device__ __forceinline__ void bar() {
    // LDS-only barrier: order ds ops but do NOT drain vmcnt (keeps x-prefetch
    // loads and y-stores in flight across the barrier).
    asm volatile("s_waitcnt lgkmcnt(0)" ::: "memory");
    __builtin_amdgcn_s_barrier();
}

// ---------------- fc1: scent[B,T,3] -> x1[T,B,32] f16 (24 real + 8 zero pad) ---------
__global__ __launch_bounds__(256) void fc1_kernel(
    const float* __restrict__ scent,
    const float* __restrict__ W1, const float* __restrict__ b1,
    const float* __restrict__ W2, const float* __restrict__ b2,
    f16* __restrict__ x1) {
    int r = blockIdx.x * 256 + threadIdx.x;   // r = b*T + t
    int b = r >> 11, t = r & 2047;
    float s0 = scent[r * 3], s1 = scent[r * 3 + 1], s2 = scent[r * 3 + 2];
    float a[12];
#pragma unroll
    for (int i = 0; i < 12; i++) {
        float v = W1[i * 3] * s0 + W1[i * 3 + 1] * s1 + W1[i * 3 + 2] * s2 + b1[i];
        a[i] = fmaxf(v, 0.f);
    }
    union { f16 o[32]; uint4 u[4]; } U;
#pragma unroll
    for (int j = 0; j < 24; j++) {
        float v = b2[j];
#pragma unroll
        for (int i = 0; i < 12; i++) v = fmaf(W2[j * 12 + i], a[i], v);
        U.o[j] = (f16)fmaxf(v, 0.f);
    }
#pragma unroll
    for (int j = 24; j < 32; j++) U.o[j] = (f16)0.f;
    uint4* d4 = (uint4*)(x1 + ((size_t)t * B + b) * 32);
#pragma unroll
    for (int i = 0; i < 4; i++) d4[i] = U.u[i];
}

// ---------------- pack Wf1 f32 -> half2 ----------------
__global__ __launch_bounds__(256) void pack_kernel(const float* __restrict__ w,
                                                   unsigned int* __restrict__ o) {
    int i = blockIdx.x * 256 + threadIdx.x;
    if (i < 4096) {
        union { h2 h; unsigned int u; } U;
        U.h[0] = (f16)w[2 * i];
        U.h[1] = (f16)w[2 * i + 1];
        o[i] = U.u;
    }
}

// ---------------- fused LSTM layer: one block (512 thr) per batch row ----------------
// thread = (grp = tid>>3 : 8-gate group, s = tid&7 : k-slice of KS elems).
// Split-tree shuffle reduce lands gate tid's sum on thread tid.
// SWZ: XOR-swizzle kvec byte addrs (b ^= ((b>>7)&3)<<4) -> slice reads hit
// 8 distinct bank-quads per ds_read_b128 (kills r1's 4-way conflict).
// amdgpu_waves_per_eu(2,2): exactly 1 block/CU -> 256-VGPR cap -> the
// KS/2*8-dword weight array stays in arch VGPRs (no AGPR shuffling).
template <int KIN, int KREAL, bool SWZ>
__global__ __attribute__((amdgpu_flat_work_group_size(512, 512), amdgpu_waves_per_eu(2, 2)))
void lstm_kernel(
    const f16* __restrict__ x,       // [T,B,KIN] f16
    const float* __restrict__ Wih,   // [512,KREAL]
    const float* __restrict__ Whh,   // [512,128]
    const float* __restrict__ bih, const float* __restrict__ bhh,
    f16* __restrict__ y,             // [T,B,128] f16 (may alias x: in-place)
    float* __restrict__ hT, float* __restrict__ cT) {  // [B,128] each
    constexpr int KTOT = KIN + HDIM;
    constexpr int KS = KTOT / 8;
    __shared__ __align__(16) f16 kvec[KTOT];   // [x_t | h_{t-1}] (byte-swizzled if SWZ)
    __shared__ float gbuf[512];

    const int tid = threadIdx.x;
    const int bb = blockIdx.x;
    const int s = tid & 7;          // k-slice index
    const int grp = tid >> 3;       // gate group (8 gates each)

    // ---- per-thread weights (f16 packed): gates grp*8+i, k in [s*KS, s*KS+KS) ----
    h2 wh[8][KS / 2];
#pragma unroll
    for (int i = 0; i < 8; i++) {
        int g = grp * 8 + i;
#pragma unroll
        for (int kk = 0; kk < KS / 2; kk++) {
            int k0 = s * KS + 2 * kk;
            int k1 = k0 + 1;
            float w0, w1;
            if (k0 < KIN) w0 = (k0 < KREAL) ? Wih[g * KREAL + k0] : 0.f;
            else          w0 = Whh[g * HDIM + (k0 - KIN)];
            if (k1 < KIN) w1 = (k1 < KREAL) ? Wih[g * KREAL + k1] : 0.f;
            else          w1 = Whh[g * HDIM + (k1 - KIN)];
            h2 p; p[0] = (f16)w0; p[1] = (f16)w1;
            wh[i][kk] = p;
        }
    }
    const float bsum = bih[tid] + bhh[tid];
    float c = 0.f;

    // ---- swizzled LDS pointers ----
    char* kB = (char*)kvec;
    // h-writer (tid<128): logical byte (KIN+tid)*2
    f16* hwp = nullptr;
    if (tid < HDIM) {
        int bw = (KIN + tid) * 2;
        int b2 = SWZ ? (bw ^ (((bw >> 7) & 3) << 4)) : bw;
        hwp = (f16*)(kB + b2);
    }
    // x stagers: dedicated lanes tid in [128, 128+KIN/2), one dword (2 f16) each
    constexpr int KIN2 = KIN / 2;
    const bool stager = (tid >= 128) && (tid < 128 + KIN2);
    const int sid = tid - 128;
    unsigned int* xwp = nullptr;
    if (stager) {
        int bw = 4 * sid;
        int b2 = SWZ ? (bw ^ (((bw >> 7) & 3) << 4)) : bw;
        xwp = (unsigned int*)(kB + b2);
    }
    // slice read addrs (SWZ path: 4x b128 per thread)
    int ra0 = 0, ra1 = 0, ra2 = 0, ra3 = 0;
    if (SWZ) {
        int c0 = 4 * s + 0, c1 = 4 * s + 1, c2 = 4 * s + 2, c3 = 4 * s + 3;
        ra0 = (c0 ^ ((c0 >> 3) & 3)) << 4;
        ra1 = (c1 ^ ((c1 >> 3) & 3)) << 4;
        ra2 = (c2 ^ ((c2 >> 3) & 3)) << 4;
        ra3 = (c3 ^ ((c3 >> 3) & 3)) << 4;
    }

    const unsigned int* xg = (const unsigned int*)x;

    if (tid < HDIM) *hwp = (f16)0.f;   // h0 = 0
    if (stager) {
        unsigned int x0 = xg[(size_t)(0 * B + bb) * KIN2 + sid];
        *xwp = x0;                     // x_0 (compiler waits vmcnt)
    }
    unsigned int xr1 = 0, xr2 = 0;     // prefetch rows t+1, t+2
    if (stager) {
        xr1 = xg[(size_t)(1 * B + bb) * KIN2 + sid];
        int t2 = (2 < T) ? 2 : T - 1;
        xr2 = xg[(size_t)t2 * B * KIN2 + (size_t)bb * KIN2 + sid];
    }
    __syncthreads();

    for (int t = 0; t < T; t++) {
        // issue prefetch for row t+3 early (hides under dot compute)
        unsigned int xr3 = 0;
        if (stager) {
            int tn = (t + 3 < T) ? t + 3 : T - 1;
            xr3 = xg[(size_t)tn * B * KIN2 + (size_t)bb * KIN2 + sid];
        }

        // ---- slice read + partial dots: 8 gates x KS ----
        float acc[8];
#pragma unroll
        for (int i = 0; i < 8; i++) acc[i] = 0.f;

        if constexpr (SWZ) {
            union { uint4 u4[4]; h2 h[16]; } S;
            S.u4[0] = *(const uint4*)(kB + ra0);
            S.u4[1] = *(const uint4*)(kB + ra1);
            S.u4[2] = *(const uint4*)(kB + ra2);
            S.u4[3] = *(const uint4*)(kB + ra3);
            static_assert(KS / 2 == 16, "swz path expects KS=32");
#pragma unroll
            for (int kk = 0; kk < 16; kk++) {
#pragma unroll
                for (int i = 0; i < 8; i++) acc[i] = dot2(wh[i][kk], S.h[kk], acc[i]);
            }
        } else {
            union { uint2 u[KS / 4]; h2 h[KS / 2]; } S;
            const uint2* kp = (const uint2*)(kvec + s * KS);
#pragma unroll
            for (int i2 = 0; i2 < KS / 4; i2++) S.u[i2] = kp[i2];
#pragma unroll
            for (int kk = 0; kk < KS / 2; kk++) {
#pragma unroll
                for (int i = 0; i < 8; i++) acc[i] = dot2(wh[i][kk], S.h[kk], acc[i]);
            }
        }

        // ---- split-tree reduce over 8 sub-lanes; lane s ends with gate grp*8+s = tid ----
        const int h4 = s & 4, h2b = s & 2, h1 = s & 1;
        float q0 = (h4 ? acc[4] : acc[0]) + __shfl_xor(h4 ? acc[0] : acc[4], 4);
        float q1 = (h4 ? acc[5] : acc[1]) + __shfl_xor(h4 ? acc[1] : acc[5], 4);
        float q2 = (h4 ? acc[6] : acc[2]) + __shfl_xor(h4 ? acc[2] : acc[6], 4);
        float q3 = (h4 ? acc[7] : acc[3]) + __shfl_xor(h4 ? acc[3] : acc[7], 4);
        float r0 = (h2b ? q2 : q0) + __shfl_xor(h2b ? q0 : q2, 2);
        float r1 = (h2b ? q3 : q1) + __shfl_xor(h2b ? q1 : q3, 2);
        float v  = (h1 ? r1 : r0) + __shfl_xor(h1 ? r0 : r1, 1);
        v += bsum;

        // ---- activation (wave-uniform gate type: tid>>7; 2=g -> tanh) ----
        const int gt = tid >> 7;
        float act = (gt == 2) ? tanh_(v) : sigm(v);
        gbuf[tid] = act;
        bar();

        // ---- c/h update (threads 0..127) ----
        if (tid < HDIM) {
            float gi = gbuf[tid], gf = gbuf[128 + tid], gg = gbuf[256 + tid], go = gbuf[384 + tid];
            c = gf * c + gi * gg;
            float hh = go * tanh_(c);
            *hwp = (f16)hh;
            y[((size_t)t * B + bb) * HDIM + tid] = (f16)hh;
            if (t == T - 1) { hT[bb * HDIM + tid] = hh; cT[bb * HDIM + tid] = c; }
        }
        if (stager) {
            *xwp = xr1;   // x_{t+1}
        }
        xr1 = xr2; xr2 = xr3;
        bar();
    }
}

// ---------------- fc2: y[T,B,128] f16 -> out[B,T,32] f32 ----------------
__global__ __launch_bounds__(256) void fc2_kernel(
    const f16* __restrict__ yin,
    const unsigned int* __restrict__ w1,  // [64][64] half2-packed Wf1
    const float* __restrict__ bf1,
    const float* __restrict__ Wf2,        // [32][64] f32
    const float* __restrict__ bf2,
    float* __restrict__ out) {
    int r = blockIdx.x * 256 + threadIdx.x;   // r = t*B + b
    union { uint4 u4[16]; h2 h[64]; } Y;
    {
        const uint4* yr4 = (const uint4*)(yin + (size_t)r * 128);
#pragma unroll
        for (int i = 0; i < 16; i++) Y.u4[i] = yr4[i];
    }
    float acc2[32];
#pragma unroll
    for (int i = 0; i < 32; i++) acc2[i] = 0.f;

    for (int cO = 0; cO < 64; cO++) {   // rolled: z1[cO] consumed immediately
        float a0 = bf1[cO], a1 = 0.f, a2 = 0.f, a3 = 0.f;
#pragma unroll
        for (int kk = 0; kk < 64; kk += 4) {
            union { unsigned int u; h2 h; } W0, W1x, W2x, W3;
            W0.u = w1[cO * 64 + kk];      a0 = dot2(W0.h,  Y.h[kk],     a0);
            W1x.u = w1[cO * 64 + kk + 1]; a1 = dot2(W1x.h, Y.h[kk + 1], a1);
            W2x.u = w1[cO * 64 + kk + 2]; a2 = dot2(W2x.h, Y.h[kk + 2], a2);
            W3.u = w1[cO * 64 + kk + 3];  a3 = dot2(W3.h,  Y.h[kk + 3], a3);
        }
        float a = fmaxf((a0 + a1) + (a2 + a3), 0.f);
#pragma unroll
        for (int c2 = 0; c2 < 32; c2++) acc2[c2] = fmaf(a, Wf2[c2 * 64 + cO], acc2[c2]);
    }
    float* orow = out + ((size_t)(r & 255) * T + (r >> 8)) * 32;
#pragma unroll
    for (int c2 = 0; c2 < 32; c2++) orow[c2] = fmaxf(acc2[c2] + bf2[c2], 0.f);
}

// ---------------- launch ----------------
extern "C" void kernel_launch(void* const* d_in, const int* in_sizes, int n_in,
                              void* d_out, int out_size, void* d_ws, size_t ws_size,
                              hipStream_t stream) {
    const float* scent = (const float*)d_in[0];
    const float* W1 = (const float*)d_in[1];
    const float* b1 = (const float*)d_in[2];
    const float* W2 = (const float*)d_in[3];
    const float* b2 = (const float*)d_in[4];
    const float* Wih[3] = {(const float*)d_in[5], (const float*)d_in[9], (const float*)d_in[13]};
    const float* Whh[3] = {(const float*)d_in[6], (const float*)d_in[10], (const float*)d_in[14]};
    const float* bihp[3] = {(const float*)d_in[7], (const float*)d_in[11], (const float*)d_in[15]};
    const float* bhhp[3] = {(const float*)d_in[8], (const float*)d_in[12], (const float*)d_in[16]};
    const float* Wf1 = (const float*)d_in[17];
    const float* bf1 = (const float*)d_in[18];
    const float* Wf2 = (const float*)d_in[19];
    const float* bf2 = (const float*)d_in[20];

    const size_t o_x1 = 0;
    const size_t o_y  = 33554432;               // T*B*32*2
    const size_t o_w1 = o_y + 134217728;        // T*B*128*2
    const size_t need = o_w1 + 16384;
    if (ws_size < need) return;

    char* ws = (char*)d_ws;
    f16* x1 = (f16*)(ws + o_x1);                // [T,B,32]
    f16* yb = (f16*)(ws + o_y);                 // [T,B,128], reused in-place per layer
    unsigned int* w1p = (unsigned int*)(ws + o_w1);

    float* out = (float*)d_out;
    float* hO = out + (size_t)B * T * 32;
    float* cO = hO + 3 * B * HDIM;

    pack_kernel<<<16, 256, 0, stream>>>(Wf1, w1p);
    fc1_kernel<<<(B * T) / 256, 256, 0, stream>>>(scent, W1, b1, W2, b2, x1);
    lstm_kernel<32, 24, false><<<B, 512, 0, stream>>>(x1, Wih[0], Whh[0], bihp[0], bhhp[0],
                                                      yb, hO, cO);
    lstm_kernel<128, 128, true><<<B, 512, 0, stream>>>(yb, Wih[1], Whh[1], bihp[1], bhhp[1],
                                                       yb, hO + B * HDIM, cO + B * HDIM);
    lstm_kernel<128, 128, true><<<B, 512, 0, stream>>>(yb, Wih[2], Whh[2], bihp[2], bhhp[2],
                                                       yb, hO + 2 * B * HDIM, cO + 2 * B * HDIM);
    fc2_kernel<<<(B * T) / 256, 256, 0, stream>>>(yb, w1p, bf1, Wf2, bf2, out);
}

// Round 4
// 4806.546 us; speedup vs baseline: 1.5611x; 1.2692x over previous
//
#include <hip/hip_runtime.h>

#define B 256
#define T 2048
#define HDIM 128

typedef _Float16 f16;
typedef _Float16 h2 __attribute__((ext_vector_type(2)));
typedef _Float16 f16x8 __attribute__((ext_vector_type(8)));
typedef float f32x4 __attribute__((ext_vector_type(4)));

__device__ __forceinline__ float dot2(h2 a, h2 b, float c) {
#if __has_builtin(__builtin_amdgcn_fdot2)
    return __builtin_amdgcn_fdot2(a, b, c, false);
#else
    return c + (float)a[0] * (float)b[0] + (float)a[1] * (float)b[1];
#endif
}

__device__ __forceinline__ float sigm(float x) { return 1.0f / (1.0f + __expf(-x)); }
__device__ __forceinline__ float tanh_(float x) {
    float e = __expf(-2.0f * fabsf(x));
    float t = (1.0f - e) / (1.0f + e);
    return copysignf(t, x);
}

__device__ __forceinline__ void bar() {
    // LDS-only barrier: order ds ops but do NOT drain vmcnt (keeps prefetch
    // loads and y-stores in flight across the barrier).
    asm volatile("s_waitcnt lgkmcnt(0)" ::: "memory");
    __builtin_amdgcn_s_barrier();
}

// ---------------- fc1: scent[B,T,3] -> x1[T,B,32] f16 (24 real + 8 zero pad) ---------
__global__ __launch_bounds__(256) void fc1_kernel(
    const float* __restrict__ scent,
    const float* __restrict__ W1, const float* __restrict__ b1,
    const float* __restrict__ W2, const float* __restrict__ b2,
    f16* __restrict__ x1) {
    int r = blockIdx.x * 256 + threadIdx.x;   // r = b*T + t
    int b = r >> 11, t = r & 2047;
    float s0 = scent[r * 3], s1 = scent[r * 3 + 1], s2 = scent[r * 3 + 2];
    float a[12];
#pragma unroll
    for (int i = 0; i < 12; i++) {
        float v = W1[i * 3] * s0 + W1[i * 3 + 1] * s1 + W1[i * 3 + 2] * s2 + b1[i];
        a[i] = fmaxf(v, 0.f);
    }
    union { f16 o[32]; uint4 u[4]; } U;
#pragma unroll
    for (int j = 0; j < 24; j++) {
        float v = b2[j];
#pragma unroll
        for (int i = 0; i < 12; i++) v = fmaf(W2[j * 12 + i], a[i], v);
        U.o[j] = (f16)fmaxf(v, 0.f);
    }
#pragma unroll
    for (int j = 24; j < 32; j++) U.o[j] = (f16)0.f;
    uint4* d4 = (uint4*)(x1 + ((size_t)t * B + b) * 32);
#pragma unroll
    for (int i = 0; i < 4; i++) d4[i] = U.u[i];
}

// ---------------- pack Wf1 f32 -> half2 ----------------
__global__ __launch_bounds__(256) void pack_kernel(const float* __restrict__ w,
                                                   unsigned int* __restrict__ o) {
    int i = blockIdx.x * 256 + threadIdx.x;
    if (i < 4096) {
        union { h2 h; unsigned int u; } U;
        U.h[0] = (f16)w[2 * i];
        U.h[1] = (f16)w[2 * i + 1];
        o[i] = U.u;
    }
}

// ---------------- fused LSTM layer: one block (512 thr) per batch row ----------------
// Serial part: only the h-half (k=128). thread = (grp=tid>>3 : 8 gates, s=tid&7 :
// 16-k slice); per-thread Whh f16 weights = 64 dwords (fits arch VGPRs).
// x-half: computed 16 steps ahead via MFMA 16x16x32_f16 on the matrix pipe:
// A = 16 time-rows of x (staged in fragment order in LDS by wave 7),
// B = Wih fragments resident in regs (4 coltiles x KF kfrags per wave).
// Result gates_x (+both biases) double-buffered in LDS, read 1 f16/thread/step.
template <int KF, int KREAL>
__global__ __attribute__((amdgpu_flat_work_group_size(512, 512), amdgpu_waves_per_eu(2, 2)))
void lstm_fused(
    const f16* __restrict__ x,       // [T,B,KIN] f16, KIN = KF*32
    const float* __restrict__ Wih,   // [512,KREAL] f32
    const float* __restrict__ Whh,   // [512,128] f32
    const float* __restrict__ bih, const float* __restrict__ bhh,
    f16* __restrict__ y,             // [T,B,128] f16
    float* __restrict__ hT, float* __restrict__ cT) {  // [B,128] each
    constexpr int KIN = KF * 32;
    __shared__ __align__(16) f16 xf[2][KF * 512];    // A-frags (phys order), 2 windows
    __shared__ __align__(16) f16 gxb[2][16 * 512];   // gates_x windows
    __shared__ __align__(16) f16 hbuf[HDIM];
    __shared__ float gbuf[512];

    const int tid = threadIdx.x, bb = blockIdx.x;
    const int l = tid & 63, wv = tid >> 6;
    const int s = tid & 7, grp = tid >> 3;
    const int lg = (l >> 4) & 3, lc = l & 15;

    // ---- B-frags (Wih) + bias, per wave: gate cols [64*wv, 64*wv+64) ----
    f16x8 bf[4][KF];
    float bias4[4];
#pragma unroll
    for (int tt = 0; tt < 4; tt++) {
        int g = 64 * wv + 16 * tt + lc;
        bias4[tt] = bih[g] + bhh[g];
#pragma unroll
        for (int kf = 0; kf < KF; kf++) {
            f16x8 v;
#pragma unroll
            for (int j = 0; j < 8; j++) {
                int k = kf * 32 + lg * 8 + j;
                v[j] = (k < KREAL) ? (f16)Wih[g * KREAL + k] : (f16)0.f;
            }
            bf[tt][kf] = v;
        }
    }
    // ---- Whh f16 per-thread weights: gates grp*8+i, k in [16s,16s+16) ----
    h2 wh[8][8];
#pragma unroll
    for (int i = 0; i < 8; i++) {
        int g = grp * 8 + i;
#pragma unroll
        for (int kk = 0; kk < 8; kk++) {
            int k = 16 * s + 2 * kk;
            h2 p; p[0] = (f16)Whh[g * HDIM + k]; p[1] = (f16)Whh[g * HDIM + k + 1];
            wh[i][kk] = p;
        }
    }
    float c = 0.f;
    if (tid < HDIM) hbuf[tid] = (f16)0.f;

    // ---- prologue: stage x window 0, compute gx window 0, stage x window 1 ----
    if (wv == 7) {
#pragma unroll
        for (int kf = 0; kf < KF; kf++) {
            uint4 vv = *(const uint4*)(x + ((size_t)(l & 15) * B + bb) * KIN + kf * 32 + lg * 8);
            *(uint4*)(&xf[0][kf * 512 + l * 8]) = vv;
        }
    }
    __syncthreads();
    {
        f16x8 af0[KF];
#pragma unroll
        for (int kf = 0; kf < KF; kf++) af0[kf] = *(const f16x8*)(&xf[0][kf * 512 + l * 8]);
#pragma unroll
        for (int tt = 0; tt < 4; tt++) {
            f32x4 a4 = {0.f, 0.f, 0.f, 0.f};
#pragma unroll
            for (int kf = 0; kf < KF; kf++)
                a4 = __builtin_amdgcn_mfma_f32_16x16x32_f16(af0[kf], bf[tt][kf], a4, 0, 0, 0);
#pragma unroll
            for (int q = 0; q < 4; q++)
                gxb[0][(4 * lg + q) * 512 + 64 * wv + 16 * tt + lc] = (f16)(a4[q] + bias4[tt]);
        }
        if (wv == 7) {
#pragma unroll
            for (int kf = 0; kf < KF; kf++) {
                uint4 vv = *(const uint4*)(x + ((size_t)(16 + (l & 15)) * B + bb) * KIN + kf * 32 + lg * 8);
                *(uint4*)(&xf[1][kf * 512 + l * 8]) = vv;
            }
        }
    }
    __syncthreads();

    // ---- main loop: 128 windows x 16 steps ----
    f16x8 af[KF];
    f32x4 acc4 = {0.f, 0.f, 0.f, 0.f};
    uint4 xr[KF];
    for (int W = 0; W < T / 16; W++) {
        const int p = W & 1;
#pragma unroll
        for (int tl = 0; tl < 16; tl++) {
            const int t = W * 16 + tl;
            // stager: issue global loads for window W+2 (hidden under compute)
            if (tl == 4 && wv == 7) {
                int twb = 16 * (W + 2) + (l & 15); if (twb > T - 1) twb = T - 1;
#pragma unroll
                for (int kf = 0; kf < KF; kf++)
                    xr[kf] = *(const uint4*)(x + ((size_t)twb * B + bb) * KIN + kf * 32 + lg * 8);
            }
            // ---- serial h-dot: slice read (2x b128, 2-way = free) + 64 dot2 ----
            union { uint4 u[2]; h2 h[8]; } S;
            S.u[0] = *(const uint4*)(&hbuf[16 * s]);
            S.u[1] = *(const uint4*)(&hbuf[16 * s + 8]);
            float gxv = (float)gxb[p][tl * 512 + tid];
            float acc[8];
#pragma unroll
            for (int i = 0; i < 8; i++) acc[i] = 0.f;
#pragma unroll
            for (int kk = 0; kk < 8; kk++) {
#pragma unroll
                for (int i = 0; i < 8; i++) acc[i] = dot2(wh[i][kk], S.h[kk], acc[i]);
            }
            // ---- window work: next window's gates_x via MFMA (matrix pipe) ----
            if (tl == 0) {
#pragma unroll
                for (int kf = 0; kf < KF; kf++)
                    af[kf] = *(const f16x8*)(&xf[(W + 1) & 1][kf * 512 + l * 8]);
            }
            if constexpr (KF == 4) {
                const int tt = tl >> 2, kf = tl & 3;
                if (kf == 0) acc4 = (f32x4){0.f, 0.f, 0.f, 0.f};
                acc4 = __builtin_amdgcn_mfma_f32_16x16x32_f16(af[kf], bf[tt][kf], acc4, 0, 0, 0);
                if (kf == 3) {
#pragma unroll
                    for (int q = 0; q < 4; q++)
                        gxb[p ^ 1][(4 * lg + q) * 512 + 64 * wv + 16 * tt + lc] =
                            (f16)(acc4[q] + bias4[tt]);
                }
            } else {
                if (tl < 4) {
                    const int tt = tl;
                    f32x4 a4 = {0.f, 0.f, 0.f, 0.f};
                    a4 = __builtin_amdgcn_mfma_f32_16x16x32_f16(af[0], bf[tt][0], a4, 0, 0, 0);
#pragma unroll
                    for (int q = 0; q < 4; q++)
                        gxb[p ^ 1][(4 * lg + q) * 512 + 64 * wv + 16 * tt + lc] =
                            (f16)(a4[q] + bias4[tt]);
                }
            }
            // stager: LDS write of window W+2 x-frags
            if (tl == 8 && wv == 7) {
#pragma unroll
                for (int kf = 0; kf < KF; kf++)
                    *(uint4*)(&xf[p][kf * 512 + l * 8]) = xr[kf];
            }
            // ---- split-tree reduce: lane s ends with gate grp*8+s = tid ----
            const int h4 = s & 4, h2b = s & 2, h1 = s & 1;
            float q0 = (h4 ? acc[4] : acc[0]) + __shfl_xor(h4 ? acc[0] : acc[4], 4);
            float q1 = (h4 ? acc[5] : acc[1]) + __shfl_xor(h4 ? acc[1] : acc[5], 4);
            float q2 = (h4 ? acc[6] : acc[2]) + __shfl_xor(h4 ? acc[2] : acc[6], 4);
            float q3 = (h4 ? acc[7] : acc[3]) + __shfl_xor(h4 ? acc[3] : acc[7], 4);
            float r0 = (h2b ? q2 : q0) + __shfl_xor(h2b ? q0 : q2, 2);
            float r1 = (h2b ? q3 : q1) + __shfl_xor(h2b ? q1 : q3, 2);
            float v  = (h1 ? r1 : r0) + __shfl_xor(h1 ? r0 : r1, 1);
            v += gxv;   // x-half + both biases (from MFMA epilogue)

            // ---- activation (wave-uniform gate type: tid>>7; 2=g -> tanh) ----
            const int gt = tid >> 7;
            float act = (gt == 2) ? tanh_(v) : sigm(v);
            gbuf[tid] = act;
            bar();

            // ---- c/h update (threads 0..127) ----
            if (tid < HDIM) {
                float gi = gbuf[tid], gf = gbuf[128 + tid], gg = gbuf[256 + tid], go = gbuf[384 + tid];
                c = gf * c + gi * gg;
                float hh = go * tanh_(c);
                hbuf[tid] = (f16)hh;
                y[((size_t)t * B + bb) * HDIM + tid] = (f16)hh;
                if (t == T - 1) { hT[bb * HDIM + tid] = hh; cT[bb * HDIM + tid] = c; }
            }
            bar();
        }
    }
}

// ---------------- fc2: y[T,B,128] f16 -> out[B,T,32] f32 ----------------
__global__ __launch_bounds__(256) void fc2_kernel(
    const f16* __restrict__ yin,
    const unsigned int* __restrict__ w1,  // [64][64] half2-packed Wf1
    const float* __restrict__ bf1,
    const float* __restrict__ Wf2,        // [32][64] f32
    const float* __restrict__ bf2,
    float* __restrict__ out) {
    int r = blockIdx.x * 256 + threadIdx.x;   // r = t*B + b
    union { uint4 u4[16]; h2 h[64]; } Y;
    {
        const uint4* yr4 = (const uint4*)(yin + (size_t)r * 128);
#pragma unroll
        for (int i = 0; i < 16; i++) Y.u4[i] = yr4[i];
    }
    float acc2[32];
#pragma unroll
    for (int i = 0; i < 32; i++) acc2[i] = 0.f;

    for (int cO = 0; cO < 64; cO++) {   // rolled: z1[cO] consumed immediately
        float a0 = bf1[cO], a1 = 0.f, a2 = 0.f, a3 = 0.f;
#pragma unroll
        for (int kk = 0; kk < 64; kk += 4) {
            union { unsigned int u; h2 h; } W0, W1x, W2x, W3;
            W0.u = w1[cO * 64 + kk];      a0 = dot2(W0.h,  Y.h[kk],     a0);
            W1x.u = w1[cO * 64 + kk + 1]; a1 = dot2(W1x.h, Y.h[kk + 1], a1);
            W2x.u = w1[cO * 64 + kk + 2]; a2 = dot2(W2x.h, Y.h[kk + 2], a2);
            W3.u = w1[cO * 64 + kk + 3];  a3 = dot2(W3.h,  Y.h[kk + 3], a3);
        }
        float a = fmaxf((a0 + a1) + (a2 + a3), 0.f);
#pragma unroll
        for (int c2 = 0; c2 < 32; c2++) acc2[c2] = fmaf(a, Wf2[c2 * 64 + cO], acc2[c2]);
    }
    float* orow = out + ((size_t)(r & 255) * T + (r >> 8)) * 32;
#pragma unroll
    for (int c2 = 0; c2 < 32; c2++) orow[c2] = fmaxf(acc2[c2] + bf2[c2], 0.f);
}

// ---------------- launch ----------------
extern "C" void kernel_launch(void* const* d_in, const int* in_sizes, int n_in,
                              void* d_out, int out_size, void* d_ws, size_t ws_size,
                              hipStream_t stream) {
    const float* scent = (const float*)d_in[0];
    const float* W1 = (const float*)d_in[1];
    const float* b1 = (const float*)d_in[2];
    const float* W2 = (const float*)d_in[3];
    const float* b2 = (const float*)d_in[4];
    const float* Wih[3] = {(const float*)d_in[5], (const float*)d_in[9], (const float*)d_in[13]};
    const float* Whh[3] = {(const float*)d_in[6], (const float*)d_in[10], (const float*)d_in[14]};
    const float* bihp[3] = {(const float*)d_in[7], (const float*)d_in[11], (const float*)d_in[15]};
    const float* bhhp[3] = {(const float*)d_in[8], (const float*)d_in[12], (const float*)d_in[16]};
    const float* Wf1 = (const float*)d_in[17];
    const float* bf1 = (const float*)d_in[18];
    const float* Wf2 = (const float*)d_in[19];
    const float* bf2 = (const float*)d_in[20];

    const size_t o_x1 = 0;
    const size_t o_y  = 33554432;               // T*B*32*2
    const size_t o_w1 = o_y + 134217728;        // T*B*128*2
    const size_t need = o_w1 + 16384;
    if (ws_size < need) return;

    char* ws = (char*)d_ws;
    f16* x1 = (f16*)(ws + o_x1);                // [T,B,32]
    f16* yb = (f16*)(ws + o_y);                 // [T,B,128], reused in-place per layer
    unsigned int* w1p = (unsigned int*)(ws + o_w1);

    float* out = (float*)d_out;
    float* hO = out + (size_t)B * T * 32;
    float* cO = hO + 3 * B * HDIM;

    pack_kernel<<<16, 256, 0, stream>>>(Wf1, w1p);
    fc1_kernel<<<(B * T) / 256, 256, 0, stream>>>(scent, W1, b1, W2, b2, x1);
    lstm_fused<1, 24><<<B, 512, 0, stream>>>(x1, Wih[0], Whh[0], bihp[0], bhhp[0],
                                             yb, hO, cO);
    lstm_fused<4, 128><<<B, 512, 0, stream>>>(yb, Wih[1], Whh[1], bihp[1], bhhp[1],
                                              yb, hO + B * HDIM, cO + B * HDIM);
    lstm_fused<4, 128><<<B, 512, 0, stream>>>(yb, Wih[2], Whh[2], bihp[2], bhhp[2],
                                              yb, hO + 2 * B * HDIM, cO + 2 * B * HDIM);
    fc2_kernel<<<(B * T) / 256, 256, 0, stream>>>(yb, w1p, bf1, Wf2, bf2, out);
}